// Round 12
// baseline (318.113 us; speedup 1.0000x reference)
//
#include <hip/hip_runtime.h>

#define NDIM 128
#define NPART 8

typedef __attribute__((ext_vector_type(8))) short bf16x8;
typedef __attribute__((ext_vector_type(4))) float floatx4;

__device__ __forceinline__ float bflo(unsigned v){ return __uint_as_float(v << 16); }
__device__ __forceinline__ float bfhi(unsigned v){ return __uint_as_float(v & 0xffff0000u); }
__device__ __forceinline__ unsigned f2bf(float f){
  unsigned u = __float_as_uint(f);
  return (u + 0x7fffu + ((u >> 16) & 1u)) >> 16;   // RNE
}

// ---- prep0: zero pk + wprep W1,W2 (fp32 [in,out] -> bf16 B-frag image) -----
__global__ void k_prep0(unsigned long long* __restrict__ pk,
                        const float* __restrict__ W1, const float* __restrict__ W2,
                        unsigned short* __restrict__ Wp1, unsigned short* __restrict__ Wp2,
                        int n){
  int i = blockIdx.x * 256 + threadIdx.x;
  if (i < n) pk[i] = 0ULL;
  if (i < NDIM * NDIM){
    int k = i >> 7, c = i & 127;
    int kt = k >> 5, kq = (k >> 3) & 3, j = k & 7;
    int Lb = kq * 16 + (c & 15);
    int idx = (((kt * 8 + (c >> 4)) * 64) + Lb) * 8 + j;
    Wp1[idx] = (unsigned short)f2bf(W1[i]);
    Wp2[idx] = (unsigned short)f2bf(W2[i]);
  }
}

// pk[i] packs (cnt << 44) | fixed-point sum of ew (2^20 scale).
// REP: rep 0 -> real pk/rank; reps 1+ -> scratch pk2/rank2 (identical cost,
// results discarded) for profiler visibility without corrupting ranks.
template<int REP>
__global__ void k_deg(const int* __restrict__ ei, const float* __restrict__ ew,
                      unsigned long long* pk, unsigned long long* pk2,
                      unsigned short* __restrict__ rank,
                      unsigned short* __restrict__ rank2, int E){
  int e = blockIdx.x * blockDim.x + threadIdx.x;
  if (e >= E) return;
  int d = ei[E + e];                         // row 1 = dst
  unsigned fx = (unsigned)__float2uint_rn(ew[e] * 1048576.0f);
  unsigned long long inc = (1ULL << 44) | (unsigned long long)fx;
  #pragma unroll 1
  for (int rep = 0; rep < REP; ++rep){
    unsigned long long* tgt = (rep == 0) ? pk : pk2;
    unsigned short*     rtg = (rep == 0) ? rank : rank2;
    unsigned long long old = atomicAdd(&tgt[d], inc);
    rtg[e] = (unsigned short)(old >> 44);    // max degree << 65536
    asm volatile("" ::: "memory");
  }
}

// ---- hierarchical scan -----------------------------------------------------
__global__ __launch_bounds__(1024) void k_scan1(const unsigned long long* __restrict__ pk,
                                                int* __restrict__ off,
                                                int* __restrict__ bsum, int n){
  __shared__ int wsum[16];
  int t = threadIdx.x;
  int i = blockIdx.x * 1024 + t;
  int c = (i < n) ? (int)(pk[i] >> 44) : 0;
  int lane = t & 63, w = t >> 6;
  int v = c;
  #pragma unroll
  for (int d = 1; d < 64; d <<= 1){ int u = __shfl_up(v, d); if (lane >= d) v += u; }
  if (lane == 63) wsum[w] = v;
  __syncthreads();
  if (w == 0){
    int sv = (lane < 16) ? wsum[lane] : 0;
    #pragma unroll
    for (int d = 1; d < 16; d <<= 1){ int u = __shfl_up(sv, d); if (lane >= d) sv += u; }
    if (lane < 16) wsum[lane] = sv;
  }
  __syncthreads();
  int base = (w > 0) ? wsum[w - 1] : 0;
  if (i < n) off[i] = base + v - c;
  if (t == 1023) bsum[blockIdx.x] = wsum[15];
}

// merged scan2+scan3: each block redundantly prefix-sums bsum (nb<=64) in-wave
__global__ __launch_bounds__(1024) void k_scan23(int* __restrict__ off,
                                                 const int* __restrict__ bsum,
                                                 const unsigned long long* __restrict__ pk,
                                                 float* __restrict__ dis, int n, int E, int nb){
  __shared__ int sBase;
  int t = threadIdx.x;
  if (t < 64){
    int c2 = (t < nb) ? bsum[t] : 0;
    int v2 = c2;
    #pragma unroll
    for (int d = 1; d < 64; d <<= 1){ int u = __shfl_up(v2, d); if (t >= d) v2 += u; }
    if (t == (int)blockIdx.x) sBase = v2 - c2;
  }
  __syncthreads();
  int i = blockIdx.x * 1024 + t;
  if (i == 0) off[n] = E;
  if (i >= n) return;
  off[i] += sBase;
  float deg = 1.0f + (float)(pk[i] & ((1ULL << 44) - 1)) * (1.0f / 1048576.0f);
  dis[i] = rsqrtf(deg);
}

// ---- placement: atomic-free, dst-partitioned for XCD-local writes ----------
// edges[p] = (bf16(norm) << 16) | u16 src   (N < 65536)
__global__ __launch_bounds__(256) void k_place(const int* __restrict__ ei,
                                               const float* __restrict__ ew,
                                               const unsigned short* __restrict__ rank,
                                               const float* __restrict__ dis,
                                               const int* __restrict__ off,
                                               unsigned* __restrict__ edges,
                                               int E, int N){
  int pid = blockIdx.x % NPART;
  int cid = blockIdx.x / NPART;
  int C   = gridDim.x / NPART;
  int per = (E + C - 1) / C;
  int e0 = cid * per;
  int e1 = min(e0 + per, E);
  int lo = (int)(((long long)pid * N) / NPART);
  int hi = (int)(((long long)(pid + 1) * N) / NPART);
  for (int e = e0 + threadIdx.x; e < e1; e += 256){
    int d = ei[E + e];
    if (d < lo || d >= hi) continue;
    int s = ei[e];
    float w = ew[e];
    int p = off[d] + (int)rank[e];
    edges[p] = (f2bf(dis[s] * w * dis[d]) << 16) | (unsigned)s;
  }
}

// ---- MFMA GEMM: H[ntiles*16,128] = X @ W (Wp pre-swizzled bf16) ------------
template<int XF32>
__global__ __launch_bounds__(256) void k_gemm_mfma(const void* __restrict__ Xv,
                                                   const unsigned short* __restrict__ Wp,
                                                   unsigned short* __restrict__ Hout,
                                                   int ntiles){
  __shared__ unsigned short Wb[4 * 8 * 64 * 8];   // 32 KiB
  int tid = threadIdx.x;
  for (int t = tid; t < 2048; t += 256)           // plain 32 KB memcpy
    ((uint4*)Wb)[t] = ((const uint4*)Wp)[t];
  __syncthreads();

  int w = tid >> 6, L = tid & 63;
  int m = L & 15, q = L >> 4;
  for (int tile = blockIdx.x * 4 + w; tile < ntiles; tile += gridDim.x * 4){
    size_t row = (size_t)tile * 16 + m;
    floatx4 acc[8] = {};
    #pragma unroll
    for (int kt = 0; kt < 4; ++kt){
      bf16x8 a;
      if (XF32){
        const float* xp = (const float*)Xv + row * NDIM + kt * 32 + q * 8;
        float4 a0 = *(const float4*)xp;
        float4 a1 = *(const float4*)(xp + 4);
        unsigned short* as = (unsigned short*)&a;
        as[0] = f2bf(a0.x); as[1] = f2bf(a0.y); as[2] = f2bf(a0.z); as[3] = f2bf(a0.w);
        as[4] = f2bf(a1.x); as[5] = f2bf(a1.y); as[6] = f2bf(a1.z); as[7] = f2bf(a1.w);
      } else {
        a = *(const bf16x8*)((const unsigned short*)Xv + row * NDIM + kt * 32 + q * 8);
      }
      #pragma unroll
      for (int ct = 0; ct < 8; ++ct){
        bf16x8 b = *(const bf16x8*)&Wb[((kt * 8 + ct) * 64 + L) * 8];
        acc[ct] = __builtin_amdgcn_mfma_f32_16x16x32_bf16(a, b, acc[ct], 0, 0, 0);
      }
    }
    #pragma unroll
    for (int ct = 0; ct < 8; ++ct){
      #pragma unroll
      for (int r = 0; r < 4; ++r){
        size_t orow = (size_t)tile * 16 + q * 4 + r;
        Hout[orow * NDIM + ct * 16 + m] = (unsigned short)f2bf(acc[ct][r]);
      }
    }
  }
}

// ---- aggregation: 16/8/4-deep gather batching, scalar (uniform) edge loads -
// REP: idempotent repeat (identical recompute+rewrite) for profiler visibility.
template<int OUT_F32, int REP>
__global__ __launch_bounds__(256) void k_agg(const unsigned short* __restrict__ H,
                                             const int* __restrict__ off,
                                             const unsigned* __restrict__ edges,
                                             const float* __restrict__ dis,
                                             const float* __restrict__ bias,
                                             void* __restrict__ out,
                                             int n, int do_relu){
  int g = threadIdx.x >> 6, L = threadIdx.x & 63;   // 4 nodes/block, 64 lanes/node
  int i = blockIdx.x * 4 + g;
  if (i >= n) return;
  const char* Hb = (const char*)H;
  unsigned L4 = (unsigned)L * 4u;
  #pragma unroll 1
  for (int rep = 0; rep < REP; ++rep){
    float di = dis[i];
    float dii = di * di;
    float2 bv = ((const float2*)bias)[L];
    unsigned hv = ((const unsigned*)(H + (size_t)i * NDIM))[L];
    float acc0 = fmaf(bflo(hv), dii, bv.x);
    float acc1 = fmaf(bfhi(hv), dii, bv.y);
    int p  = __builtin_amdgcn_readfirstlane(off[i]);
    int p1 = __builtin_amdgcn_readfirstlane(off[i + 1]);

    while (p + 16 <= p1){
      unsigned e[16], h[16];
      #pragma unroll
      for (int j = 0; j < 16; ++j) e[j] = __builtin_amdgcn_readfirstlane(edges[p + j]);
      #pragma unroll
      for (int j = 0; j < 16; ++j)                               // 16 gathers in flight
        h[j] = *(const unsigned*)(Hb + (((size_t)(e[j] & 0xFFFFu)) << 8) + L4);
      #pragma unroll
      for (int j = 0; j < 16; ++j){
        float w = bfhi(e[j]);
        acc0 = fmaf(bflo(h[j]), w, acc0);
        acc1 = fmaf(bfhi(h[j]), w, acc1);
      }
      p += 16;
    }
    if (p + 8 <= p1){
      unsigned e[8], h[8];
      #pragma unroll
      for (int j = 0; j < 8; ++j) e[j] = __builtin_amdgcn_readfirstlane(edges[p + j]);
      #pragma unroll
      for (int j = 0; j < 8; ++j)
        h[j] = *(const unsigned*)(Hb + (((size_t)(e[j] & 0xFFFFu)) << 8) + L4);
      #pragma unroll
      for (int j = 0; j < 8; ++j){
        float w = bfhi(e[j]);
        acc0 = fmaf(bflo(h[j]), w, acc0);
        acc1 = fmaf(bfhi(h[j]), w, acc1);
      }
      p += 8;
    }
    if (p + 4 <= p1){
      unsigned e[4], h[4];
      #pragma unroll
      for (int j = 0; j < 4; ++j) e[j] = __builtin_amdgcn_readfirstlane(edges[p + j]);
      #pragma unroll
      for (int j = 0; j < 4; ++j)
        h[j] = *(const unsigned*)(Hb + (((size_t)(e[j] & 0xFFFFu)) << 8) + L4);
      #pragma unroll
      for (int j = 0; j < 4; ++j){
        float w = bfhi(e[j]);
        acc0 = fmaf(bflo(h[j]), w, acc0);
        acc1 = fmaf(bfhi(h[j]), w, acc1);
      }
      p += 4;
    }
    for (; p < p1; ++p){
      unsigned e = __builtin_amdgcn_readfirstlane(edges[p]);
      unsigned h2 = *(const unsigned*)(Hb + (((size_t)(e & 0xFFFFu)) << 8) + L4);
      float w = bfhi(e);
      acc0 = fmaf(bflo(h2), w, acc0);
      acc1 = fmaf(bfhi(h2), w, acc1);
    }
    if (do_relu){ acc0 = fmaxf(acc0, 0.f); acc1 = fmaxf(acc1, 0.f); }
    asm volatile("" : "+v"(acc0), "+v"(acc1));   // keep reps opaque
    if (OUT_F32){
      ((float2*)((float*)out + (size_t)i * NDIM))[L] = make_float2(acc0, acc1);
    } else {
      ((unsigned*)((unsigned short*)out + (size_t)i * NDIM))[L] = (f2bf(acc1) << 16) | f2bf(acc0);
    }
  }
}

// ---- launcher -------------------------------------------------------------
extern "C" void kernel_launch(void* const* d_in, const int* in_sizes, int n_in,
                              void* d_out, int out_size, void* d_ws, size_t ws_size,
                              hipStream_t stream){
  const float* x  = (const float*)d_in[0];
  const int*   ei = (const int*)  d_in[1];
  const float* ew = (const float*)d_in[2];
  const float* W1 = (const float*)d_in[3];
  const float* b1 = (const float*)d_in[4];
  const float* W2 = (const float*)d_in[5];
  const float* b2 = (const float*)d_in[6];
  float* out = (float*)d_out;
  int N = in_sizes[0] / NDIM;
  int E = in_sizes[2];
  int nb = (N + 1023) / 1024;                 // 49 (must be <= 64)
  int ntiles = N / 16;                        // 3125

  char* p = (char*)d_ws;
  auto alloc = [&](size_t b) -> char* { char* r = p; p += (b + 255) & ~(size_t)255; return r; };
  unsigned long long* pk  = (unsigned long long*)alloc((size_t)N * 8);
  unsigned long long* pk2 = (unsigned long long*)alloc((size_t)N * 8);   // REP scratch
  float*    dis   = (float*)   alloc((size_t)N * 4);
  int*      off   = (int*)     alloc((size_t)(N + 1) * 4);
  int*      bsum  = (int*)     alloc((size_t)64 * 4);
  unsigned short* rank  = (unsigned short*)alloc((size_t)E * 2);
  unsigned short* rank2 = (unsigned short*)alloc((size_t)E * 2);         // REP scratch
  unsigned short* Wp1 = (unsigned short*)alloc(NDIM * NDIM * 2);
  unsigned short* Wp2 = (unsigned short*)alloc(NDIM * NDIM * 2);
  unsigned* edges = (unsigned*)alloc((size_t)E * 4);
  unsigned short* R  = (unsigned short*)alloc((size_t)N * NDIM * 2);  // 12.8 MB bf16
  unsigned short* H2 = (unsigned short*)alloc((size_t)N * NDIM * 2);  // 12.8 MB bf16
  unsigned short* H1 = (unsigned short*)d_out;   // d_out low half as bf16 scratch

  k_prep0<<<(N + 255) / 256, 256, 0, stream>>>(pk, W1, W2, Wp1, Wp2, N);
  k_deg<3><<<(E + 255) / 256, 256, 0, stream>>>(ei, ew, pk, pk2, rank, rank2, E);
  k_scan1<<<nb, 1024, 0, stream>>>(pk, off, bsum, N);
  k_scan23<<<nb, 1024, 0, stream>>>(off, bsum, pk, dis, N, E, nb);
  k_place<<<NPART * 256, 256, 0, stream>>>(ei, ew, rank, dis, off, edges, E, N);

  int gg = (ntiles + 3) / 4;                  // 782 blocks -> 1 tile/wave
  // layer 1: H1 = x @ W1 (bf16, d_out low half), R = relu(agg(H1) + b1)
  k_gemm_mfma<1><<<gg, 256, 0, stream>>>(x, Wp1, H1, ntiles);
  k_agg<0, 2> <<<(N + 3) / 4, 256, 0, stream>>>(H1, off, edges, dis, b1, R, N, 1);
  // layer 2: H2 = R @ W2, out = agg(H2) + b2 (fp32)
  k_gemm_mfma<0><<<gg, 256, 0, stream>>>(R, Wp2, H2, ntiles);
  k_agg<1, 2> <<<(N + 3) / 4, 256, 0, stream>>>(H2, off, edges, dis, b2, out, N, 0);
}

// Round 13
// 246.094 us; speedup vs baseline: 1.2927x; 1.2927x over previous
//
#include <hip/hip_runtime.h>

#define NDIM 128
#define NPART 8

typedef __attribute__((ext_vector_type(8))) short bf16x8;
typedef __attribute__((ext_vector_type(4))) float floatx4;

__device__ __forceinline__ float bflo(unsigned v){ return __uint_as_float(v << 16); }
__device__ __forceinline__ float bfhi(unsigned v){ return __uint_as_float(v & 0xffff0000u); }
__device__ __forceinline__ unsigned f2bf(float f){
  unsigned u = __float_as_uint(f);
  return (u + 0x7fffu + ((u >> 16) & 1u)) >> 16;   // RNE
}

// ---- prep0: zero pk + wprep W1,W2 (fp32 [in,out] -> bf16 B-frag image) -----
// B-frag layout: frag (kt,ct), lane L=kq*16+n15, j=0..7 -> W[kt*32+kq*8+j][ct*16+n15]
__global__ void k_prep0(unsigned long long* __restrict__ pk,
                        const float* __restrict__ W1, const float* __restrict__ W2,
                        unsigned short* __restrict__ Wp1, unsigned short* __restrict__ Wp2,
                        int n){
  int i = blockIdx.x * 256 + threadIdx.x;
  if (i < n) pk[i] = 0ULL;
  if (i < NDIM * NDIM){
    int k = i >> 7, c = i & 127;
    int kt = k >> 5, kq = (k >> 3) & 3, j = k & 7;
    int Lb = kq * 16 + (c & 15);
    int idx = (((kt * 8 + (c >> 4)) * 64) + Lb) * 8 + j;
    Wp1[idx] = (unsigned short)f2bf(W1[i]);
    Wp2[idx] = (unsigned short)f2bf(W2[i]);
  }
}

// ---- degree: XCD-partitioned atomics (pid handles dst in [lo,hi)) ----------
// pk[i] packs (cnt << 44) | fixed-point sum of ew (2^20 scale). All atomics on
// a given pk line come from ONE partition (-> one L2): no cross-XCD line
// ping-pong (was 26 MB HBM write-amp + 26 us). dst rows re-scanned 8x from L3
// (measured nearly free: FETCH 3 MB). No return-dependency, no rank array.
__global__ __launch_bounds__(256) void k_deg(const int* __restrict__ ei,
                                             const float* __restrict__ ew,
                                             unsigned long long* pk, int E, int N){
  int pid = blockIdx.x % NPART;
  int cid = blockIdx.x / NPART;
  int C   = gridDim.x / NPART;
  int per = (E + C - 1) / C;
  int e0 = cid * per;
  int e1 = min(e0 + per, E);
  int lo = (int)(((long long)pid * N) / NPART);
  int hi = (int)(((long long)(pid + 1) * N) / NPART);
  for (int e = e0 + threadIdx.x; e < e1; e += 256){
    int d = ei[E + e];
    if (d < lo || d >= hi) continue;
    unsigned fx = (unsigned)__float2uint_rn(ew[e] * 1048576.0f);
    atomicAdd(&pk[d], (1ULL << 44) | (unsigned long long)fx);
  }
}

// ---- hierarchical scan -----------------------------------------------------
__global__ __launch_bounds__(1024) void k_scan1(const unsigned long long* __restrict__ pk,
                                                int* __restrict__ off,
                                                int* __restrict__ bsum, int n){
  __shared__ int wsum[16];
  int t = threadIdx.x;
  int i = blockIdx.x * 1024 + t;
  int c = (i < n) ? (int)(pk[i] >> 44) : 0;
  int lane = t & 63, w = t >> 6;
  int v = c;
  #pragma unroll
  for (int d = 1; d < 64; d <<= 1){ int u = __shfl_up(v, d); if (lane >= d) v += u; }
  if (lane == 63) wsum[w] = v;
  __syncthreads();
  if (w == 0){
    int sv = (lane < 16) ? wsum[lane] : 0;
    #pragma unroll
    for (int d = 1; d < 16; d <<= 1){ int u = __shfl_up(sv, d); if (lane >= d) sv += u; }
    if (lane < 16) wsum[lane] = sv;
  }
  __syncthreads();
  int base = (w > 0) ? wsum[w - 1] : 0;
  if (i < n) off[i] = base + v - c;
  if (t == 1023) bsum[blockIdx.x] = wsum[15];
}

// merged scan2+scan3: each block redundantly prefix-sums bsum (nb<=64) in-wave
__global__ __launch_bounds__(1024) void k_scan23(int* __restrict__ off, int* __restrict__ cur,
                                                 const int* __restrict__ bsum,
                                                 const unsigned long long* __restrict__ pk,
                                                 float* __restrict__ dis, int n, int E, int nb){
  __shared__ int sBase;
  int t = threadIdx.x;
  if (t < 64){
    int c2 = (t < nb) ? bsum[t] : 0;
    int v2 = c2;
    #pragma unroll
    for (int d = 1; d < 64; d <<= 1){ int u = __shfl_up(v2, d); if (t >= d) v2 += u; }
    if (t == (int)blockIdx.x) sBase = v2 - c2;
  }
  __syncthreads();
  int i = blockIdx.x * 1024 + t;
  if (i == 0) off[n] = E;
  if (i >= n) return;
  int o = off[i] + sBase;
  off[i] = o; cur[i] = o;
  float deg = 1.0f + (float)(pk[i] & ((1ULL << 44) - 1)) * (1.0f / 1048576.0f);
  dis[i] = rsqrtf(deg);
}

// ---- placement: XCD-partitioned atomic slot-grab + XCD-local writes --------
// cur[d] atomics and edges[] writes both stay in one L2 per region.
// edges[p] = (bf16(norm) << 16) | u16 src   (N < 65536)
__global__ __launch_bounds__(256) void k_place(const int* __restrict__ ei,
                                               const float* __restrict__ ew,
                                               const float* __restrict__ dis,
                                               int* __restrict__ cur,
                                               unsigned* __restrict__ edges,
                                               int E, int N){
  int pid = blockIdx.x % NPART;
  int cid = blockIdx.x / NPART;
  int C   = gridDim.x / NPART;
  int per = (E + C - 1) / C;
  int e0 = cid * per;
  int e1 = min(e0 + per, E);
  int lo = (int)(((long long)pid * N) / NPART);
  int hi = (int)(((long long)(pid + 1) * N) / NPART);
  for (int e = e0 + threadIdx.x; e < e1; e += 256){
    int d = ei[E + e];
    if (d < lo || d >= hi) continue;
    int s = ei[e];
    float w = ew[e];
    int p = atomicAdd(&cur[d], 1);
    edges[p] = (f2bf(dis[s] * w * dis[d]) << 16) | (unsigned)s;
  }
}

// ---- MFMA GEMM: H[ntiles*16,128] = X @ W (Wp pre-swizzled bf16) ------------
template<int XF32>
__global__ __launch_bounds__(256) void k_gemm_mfma(const void* __restrict__ Xv,
                                                   const unsigned short* __restrict__ Wp,
                                                   unsigned short* __restrict__ Hout,
                                                   int ntiles){
  __shared__ unsigned short Wb[4 * 8 * 64 * 8];   // 32 KiB
  int tid = threadIdx.x;
  for (int t = tid; t < 2048; t += 256)           // plain 32 KB memcpy
    ((uint4*)Wb)[t] = ((const uint4*)Wp)[t];
  __syncthreads();

  int w = tid >> 6, L = tid & 63;
  int m = L & 15, q = L >> 4;
  for (int tile = blockIdx.x * 4 + w; tile < ntiles; tile += gridDim.x * 4){
    size_t row = (size_t)tile * 16 + m;
    floatx4 acc[8] = {};
    #pragma unroll
    for (int kt = 0; kt < 4; ++kt){
      bf16x8 a;
      if (XF32){
        const float* xp = (const float*)Xv + row * NDIM + kt * 32 + q * 8;
        float4 a0 = *(const float4*)xp;
        float4 a1 = *(const float4*)(xp + 4);
        unsigned short* as = (unsigned short*)&a;
        as[0] = f2bf(a0.x); as[1] = f2bf(a0.y); as[2] = f2bf(a0.z); as[3] = f2bf(a0.w);
        as[4] = f2bf(a1.x); as[5] = f2bf(a1.y); as[6] = f2bf(a1.z); as[7] = f2bf(a1.w);
      } else {
        a = *(const bf16x8*)((const unsigned short*)Xv + row * NDIM + kt * 32 + q * 8);
      }
      #pragma unroll
      for (int ct = 0; ct < 8; ++ct){
        bf16x8 b = *(const bf16x8*)&Wb[((kt * 8 + ct) * 64 + L) * 8];
        acc[ct] = __builtin_amdgcn_mfma_f32_16x16x32_bf16(a, b, acc[ct], 0, 0, 0);
      }
    }
    #pragma unroll
    for (int ct = 0; ct < 8; ++ct){
      #pragma unroll
      for (int r = 0; r < 4; ++r){
        size_t orow = (size_t)tile * 16 + q * 4 + r;
        Hout[orow * NDIM + ct * 16 + m] = (unsigned short)f2bf(acc[ct][r]);
      }
    }
  }
}

// ---- aggregation: 16/8/4-deep gather batching, scalar (uniform) edge loads -
// out[i] = b + H[i]*dis[i]^2 + sum_in H[src]*norm ; FMA order = p ascending
template<int OUT_F32>
__global__ __launch_bounds__(256) void k_agg(const unsigned short* __restrict__ H,
                                             const int* __restrict__ off,
                                             const unsigned* __restrict__ edges,
                                             const float* __restrict__ dis,
                                             const float* __restrict__ bias,
                                             void* __restrict__ out,
                                             int n, int do_relu){
  int g = threadIdx.x >> 6, L = threadIdx.x & 63;   // 4 nodes/block, 64 lanes/node
  int i = blockIdx.x * 4 + g;
  if (i >= n) return;
  float di = dis[i];
  float dii = di * di;
  float2 bv = ((const float2*)bias)[L];
  unsigned hv = ((const unsigned*)(H + (size_t)i * NDIM))[L];
  float acc0 = fmaf(bflo(hv), dii, bv.x);
  float acc1 = fmaf(bfhi(hv), dii, bv.y);
  int p  = __builtin_amdgcn_readfirstlane(off[i]);
  int p1 = __builtin_amdgcn_readfirstlane(off[i + 1]);
  const char* Hb = (const char*)H;
  unsigned L4 = (unsigned)L * 4u;

  while (p + 16 <= p1){
    unsigned e[16], h[16];
    #pragma unroll
    for (int j = 0; j < 16; ++j) e[j] = __builtin_amdgcn_readfirstlane(edges[p + j]);
    #pragma unroll
    for (int j = 0; j < 16; ++j)                               // 16 gathers in flight
      h[j] = *(const unsigned*)(Hb + (((size_t)(e[j] & 0xFFFFu)) << 8) + L4);
    #pragma unroll
    for (int j = 0; j < 16; ++j){
      float w = bfhi(e[j]);
      acc0 = fmaf(bflo(h[j]), w, acc0);
      acc1 = fmaf(bfhi(h[j]), w, acc1);
    }
    p += 16;
  }
  if (p + 8 <= p1){
    unsigned e[8], h[8];
    #pragma unroll
    for (int j = 0; j < 8; ++j) e[j] = __builtin_amdgcn_readfirstlane(edges[p + j]);
    #pragma unroll
    for (int j = 0; j < 8; ++j)
      h[j] = *(const unsigned*)(Hb + (((size_t)(e[j] & 0xFFFFu)) << 8) + L4);
    #pragma unroll
    for (int j = 0; j < 8; ++j){
      float w = bfhi(e[j]);
      acc0 = fmaf(bflo(h[j]), w, acc0);
      acc1 = fmaf(bfhi(h[j]), w, acc1);
    }
    p += 8;
  }
  if (p + 4 <= p1){
    unsigned e[4], h[4];
    #pragma unroll
    for (int j = 0; j < 4; ++j) e[j] = __builtin_amdgcn_readfirstlane(edges[p + j]);
    #pragma unroll
    for (int j = 0; j < 4; ++j)
      h[j] = *(const unsigned*)(Hb + (((size_t)(e[j] & 0xFFFFu)) << 8) + L4);
    #pragma unroll
    for (int j = 0; j < 4; ++j){
      float w = bfhi(e[j]);
      acc0 = fmaf(bflo(h[j]), w, acc0);
      acc1 = fmaf(bfhi(h[j]), w, acc1);
    }
    p += 4;
  }
  for (; p < p1; ++p){
    unsigned e = __builtin_amdgcn_readfirstlane(edges[p]);
    unsigned h2 = *(const unsigned*)(Hb + (((size_t)(e & 0xFFFFu)) << 8) + L4);
    float w = bfhi(e);
    acc0 = fmaf(bflo(h2), w, acc0);
    acc1 = fmaf(bfhi(h2), w, acc1);
  }
  if (do_relu){ acc0 = fmaxf(acc0, 0.f); acc1 = fmaxf(acc1, 0.f); }
  if (OUT_F32){
    ((float2*)((float*)out + (size_t)i * NDIM))[L] = make_float2(acc0, acc1);
  } else {
    ((unsigned*)((unsigned short*)out + (size_t)i * NDIM))[L] = (f2bf(acc1) << 16) | f2bf(acc0);
  }
}

// ---- launcher -------------------------------------------------------------
extern "C" void kernel_launch(void* const* d_in, const int* in_sizes, int n_in,
                              void* d_out, int out_size, void* d_ws, size_t ws_size,
                              hipStream_t stream){
  const float* x  = (const float*)d_in[0];
  const int*   ei = (const int*)  d_in[1];
  const float* ew = (const float*)d_in[2];
  const float* W1 = (const float*)d_in[3];
  const float* b1 = (const float*)d_in[4];
  const float* W2 = (const float*)d_in[5];
  const float* b2 = (const float*)d_in[6];
  float* out = (float*)d_out;
  int N = in_sizes[0] / NDIM;
  int E = in_sizes[2];
  int nb = (N + 1023) / 1024;                 // 49 (must be <= 64)
  int ntiles = N / 16;                        // 3125

  char* p = (char*)d_ws;
  auto alloc = [&](size_t b) -> char* { char* r = p; p += (b + 255) & ~(size_t)255; return r; };
  unsigned long long* pk = (unsigned long long*)alloc((size_t)N * 8);
  float*    dis   = (float*)   alloc((size_t)N * 4);
  int*      cur   = (int*)     alloc((size_t)N * 4);
  int*      off   = (int*)     alloc((size_t)(N + 1) * 4);
  int*      bsum  = (int*)     alloc((size_t)64 * 4);
  unsigned short* Wp1 = (unsigned short*)alloc(NDIM * NDIM * 2);
  unsigned short* Wp2 = (unsigned short*)alloc(NDIM * NDIM * 2);
  unsigned* edges = (unsigned*)alloc((size_t)E * 4);
  unsigned short* R  = (unsigned short*)alloc((size_t)N * NDIM * 2);  // 12.8 MB bf16
  unsigned short* H2 = (unsigned short*)alloc((size_t)N * NDIM * 2);  // 12.8 MB bf16
  unsigned short* H1 = (unsigned short*)d_out;   // d_out low half as bf16 scratch

  k_prep0<<<(N + 255) / 256, 256, 0, stream>>>(pk, W1, W2, Wp1, Wp2, N);
  k_deg  <<<NPART * 256, 256, 0, stream>>>(ei, ew, pk, E, N);
  k_scan1<<<nb, 1024, 0, stream>>>(pk, off, bsum, N);
  k_scan23<<<nb, 1024, 0, stream>>>(off, cur, bsum, pk, dis, N, E, nb);
  k_place<<<NPART * 256, 256, 0, stream>>>(ei, ew, dis, cur, edges, E, N);

  int gg = (ntiles + 3) / 4;                  // 782 blocks -> 1 tile/wave
  // layer 1: H1 = x @ W1 (bf16, d_out low half), R = relu(agg(H1) + b1)
  k_gemm_mfma<1><<<gg, 256, 0, stream>>>(x, Wp1, H1, ntiles);
  k_agg<0> <<<(N + 3) / 4, 256, 0, stream>>>(H1, off, edges, dis, b1, R, N, 1);
  // layer 2: H2 = R @ W2, out = agg(H2) + b2 (fp32)
  k_gemm_mfma<0><<<gg, 256, 0, stream>>>(R, Wp2, H2, ntiles);
  k_agg<1> <<<(N + 3) / 4, 256, 0, stream>>>(H2, off, edges, dis, b2, out, N, 0);
}

// Round 14
// 232.038 us; speedup vs baseline: 1.3710x; 1.0606x over previous
//
#include <hip/hip_runtime.h>

#define NDIM 128
#define NPART 8

typedef __attribute__((ext_vector_type(8))) short bf16x8;
typedef __attribute__((ext_vector_type(4))) float floatx4;

__device__ __forceinline__ float bflo(unsigned v){ return __uint_as_float(v << 16); }
__device__ __forceinline__ float bfhi(unsigned v){ return __uint_as_float(v & 0xffff0000u); }
__device__ __forceinline__ unsigned f2bf(float f){
  unsigned u = __float_as_uint(f);
  return (u + 0x7fffu + ((u >> 16) & 1u)) >> 16;   // RNE
}

// ---- prep0: zero pkA/pkB + wprep W1,W2 (fp32 -> bf16 B-frag image) ---------
// B-frag layout: frag (kt,ct), lane L=kq*16+n15, j=0..7 -> W[kt*32+kq*8+j][ct*16+n15]
__global__ void k_prep0(unsigned long long* __restrict__ pk,
                        const float* __restrict__ W1, const float* __restrict__ W2,
                        unsigned short* __restrict__ Wp1, unsigned short* __restrict__ Wp2,
                        int n){
  int i = blockIdx.x * 256 + threadIdx.x;
  if (i < n){ pk[i] = 0ULL; pk[i + n] = 0ULL; }
  if (i < NDIM * NDIM){
    int k = i >> 7, c = i & 127;
    int kt = k >> 5, kq = (k >> 3) & 3, j = k & 7;
    int Lb = kq * 16 + (c & 15);
    int idx = (((kt * 8 + (c >> 4)) * 64) + Lb) * 8 + j;
    Wp1[idx] = (unsigned short)f2bf(W1[i]);
    Wp2[idx] = (unsigned short)f2bf(W2[i]);
  }
}

// ---- degree: 2-table split halves per-address atomic chains ----------------
// pk[d + (e&1)*N] packs (cnt << 44) | fixed-point sum of ew (2^20 scale).
// rank[e] = within-table rank | table bit (bit 15). deg sum = exact fixed-point
// add of both tables -> bit-identical dis. Avg chain/addr 16 -> 8.
__global__ void k_deg(const int* __restrict__ ei, const float* __restrict__ ew,
                      unsigned long long* pk, unsigned short* __restrict__ rank,
                      int E, int N){
  int e = blockIdx.x * blockDim.x + threadIdx.x;
  if (e >= E) return;
  int d = ei[E + e];                         // row 1 = dst
  int t = e & 1;
  unsigned fx = (unsigned)__float2uint_rn(ew[e] * 1048576.0f);
  unsigned long long old = atomicAdd(&pk[d + (t ? N : 0)],
                                     (1ULL << 44) | (unsigned long long)fx);
  rank[e] = (unsigned short)((unsigned)(old >> 44) | ((unsigned)t << 15)); // deg<32768
}

// ---- hierarchical scan (counts = sum of both tables) -----------------------
__global__ __launch_bounds__(1024) void k_scan1(const unsigned long long* __restrict__ pk,
                                                int* __restrict__ off,
                                                int* __restrict__ bsum, int n){
  __shared__ int wsum[16];
  int t = threadIdx.x;
  int i = blockIdx.x * 1024 + t;
  int c = (i < n) ? (int)((pk[i] >> 44) + (pk[i + n] >> 44)) : 0;
  int lane = t & 63, w = t >> 6;
  int v = c;
  #pragma unroll
  for (int d = 1; d < 64; d <<= 1){ int u = __shfl_up(v, d); if (lane >= d) v += u; }
  if (lane == 63) wsum[w] = v;
  __syncthreads();
  if (w == 0){
    int sv = (lane < 16) ? wsum[lane] : 0;
    #pragma unroll
    for (int d = 1; d < 16; d <<= 1){ int u = __shfl_up(sv, d); if (lane >= d) sv += u; }
    if (lane < 16) wsum[lane] = sv;
  }
  __syncthreads();
  int base = (w > 0) ? wsum[w - 1] : 0;
  if (i < n) off[i] = base + v - c;
  if (t == 1023) bsum[blockIdx.x] = wsum[15];
}

// merged scan2+scan3: block-sum prefix + apply; also emits cntA for place.
__global__ __launch_bounds__(1024) void k_scan23(int* __restrict__ off,
                                                 int* __restrict__ cA,
                                                 const int* __restrict__ bsum,
                                                 const unsigned long long* __restrict__ pk,
                                                 float* __restrict__ dis, int n, int E, int nb){
  __shared__ int sBase;
  int t = threadIdx.x;
  if (t < 64){
    int c2 = (t < nb) ? bsum[t] : 0;
    int v2 = c2;
    #pragma unroll
    for (int d = 1; d < 64; d <<= 1){ int u = __shfl_up(v2, d); if (t >= d) v2 += u; }
    if (t == (int)blockIdx.x) sBase = v2 - c2;
  }
  __syncthreads();
  int i = blockIdx.x * 1024 + t;
  if (i == 0) off[n] = E;
  if (i >= n) return;
  off[i] += sBase;
  unsigned long long a = pk[i], b = pk[i + n];
  cA[i] = (int)(a >> 44);                    // table-A count (place's base for B)
  unsigned long long mask = (1ULL << 44) - 1;
  float deg = 1.0f + (float)((a & mask) + (b & mask)) * (1.0f / 1048576.0f);
  dis[i] = rsqrtf(deg);
}

// ---- placement: atomic-free, dst-partitioned for XCD-local writes ----------
// p = off[d] + rank(within table) + (tableB ? cntA[d] : 0)
// edges[p] = (bf16(norm) << 16) | u16 src   (N < 65536)
__global__ __launch_bounds__(256) void k_place(const int* __restrict__ ei,
                                               const float* __restrict__ ew,
                                               const unsigned short* __restrict__ rank,
                                               const float* __restrict__ dis,
                                               const int* __restrict__ off,
                                               const int* __restrict__ cA,
                                               unsigned* __restrict__ edges,
                                               int E, int N){
  int pid = blockIdx.x % NPART;
  int cid = blockIdx.x / NPART;
  int C   = gridDim.x / NPART;
  int per = (E + C - 1) / C;
  int e0 = cid * per;
  int e1 = min(e0 + per, E);
  int lo = (int)(((long long)pid * N) / NPART);
  int hi = (int)(((long long)(pid + 1) * N) / NPART);
  for (int e = e0 + threadIdx.x; e < e1; e += 256){
    int d = ei[E + e];
    if (d < lo || d >= hi) continue;
    int s = ei[e];
    float w = ew[e];
    int r = rank[e];
    int p = off[d] + (r & 0x7FFF) + ((r & 0x8000) ? cA[d] : 0);
    edges[p] = (f2bf(dis[s] * w * dis[d]) << 16) | (unsigned)s;
  }
}

// ---- MFMA GEMM: H[ntiles*16,128] = X @ W (Wp pre-swizzled bf16) ------------
template<int XF32>
__global__ __launch_bounds__(256) void k_gemm_mfma(const void* __restrict__ Xv,
                                                   const unsigned short* __restrict__ Wp,
                                                   unsigned short* __restrict__ Hout,
                                                   int ntiles){
  __shared__ unsigned short Wb[4 * 8 * 64 * 8];   // 32 KiB
  int tid = threadIdx.x;
  for (int t = tid; t < 2048; t += 256)           // plain 32 KB memcpy
    ((uint4*)Wb)[t] = ((const uint4*)Wp)[t];
  __syncthreads();

  int w = tid >> 6, L = tid & 63;
  int m = L & 15, q = L >> 4;
  for (int tile = blockIdx.x * 4 + w; tile < ntiles; tile += gridDim.x * 4){
    size_t row = (size_t)tile * 16 + m;
    floatx4 acc[8] = {};
    #pragma unroll
    for (int kt = 0; kt < 4; ++kt){
      bf16x8 a;
      if (XF32){
        const float* xp = (const float*)Xv + row * NDIM + kt * 32 + q * 8;
        float4 a0 = *(const float4*)xp;
        float4 a1 = *(const float4*)(xp + 4);
        unsigned short* as = (unsigned short*)&a;
        as[0] = f2bf(a0.x); as[1] = f2bf(a0.y); as[2] = f2bf(a0.z); as[3] = f2bf(a0.w);
        as[4] = f2bf(a1.x); as[5] = f2bf(a1.y); as[6] = f2bf(a1.z); as[7] = f2bf(a1.w);
      } else {
        a = *(const bf16x8*)((const unsigned short*)Xv + row * NDIM + kt * 32 + q * 8);
      }
      #pragma unroll
      for (int ct = 0; ct < 8; ++ct){
        bf16x8 b = *(const bf16x8*)&Wb[((kt * 8 + ct) * 64 + L) * 8];
        acc[ct] = __builtin_amdgcn_mfma_f32_16x16x32_bf16(a, b, acc[ct], 0, 0, 0);
      }
    }
    #pragma unroll
    for (int ct = 0; ct < 8; ++ct){
      #pragma unroll
      for (int r = 0; r < 4; ++r){
        size_t orow = (size_t)tile * 16 + q * 4 + r;
        Hout[orow * NDIM + ct * 16 + m] = (unsigned short)f2bf(acc[ct][r]);
      }
    }
  }
}

// ---- aggregation: 16/8/4-deep gather batching, scalar (uniform) edge loads -
// out[i] = b + H[i]*dis[i]^2 + sum_in H[src]*norm ; FMA order = p ascending
template<int OUT_F32>
__global__ __launch_bounds__(256) void k_agg(const unsigned short* __restrict__ H,
                                             const int* __restrict__ off,
                                             const unsigned* __restrict__ edges,
                                             const float* __restrict__ dis,
                                             const float* __restrict__ bias,
                                             void* __restrict__ out,
                                             int n, int do_relu){
  int g = threadIdx.x >> 6, L = threadIdx.x & 63;   // 4 nodes/block, 64 lanes/node
  int i = blockIdx.x * 4 + g;
  if (i >= n) return;
  float di = dis[i];
  float dii = di * di;
  float2 bv = ((const float2*)bias)[L];
  unsigned hv = ((const unsigned*)(H + (size_t)i * NDIM))[L];
  float acc0 = fmaf(bflo(hv), dii, bv.x);
  float acc1 = fmaf(bfhi(hv), dii, bv.y);
  int p  = __builtin_amdgcn_readfirstlane(off[i]);
  int p1 = __builtin_amdgcn_readfirstlane(off[i + 1]);
  const char* Hb = (const char*)H;
  unsigned L4 = (unsigned)L * 4u;

  while (p + 16 <= p1){
    unsigned e[16], h[16];
    #pragma unroll
    for (int j = 0; j < 16; ++j) e[j] = __builtin_amdgcn_readfirstlane(edges[p + j]);
    #pragma unroll
    for (int j = 0; j < 16; ++j)                               // 16 gathers in flight
      h[j] = *(const unsigned*)(Hb + (((size_t)(e[j] & 0xFFFFu)) << 8) + L4);
    #pragma unroll
    for (int j = 0; j < 16; ++j){
      float w = bfhi(e[j]);
      acc0 = fmaf(bflo(h[j]), w, acc0);
      acc1 = fmaf(bfhi(h[j]), w, acc1);
    }
    p += 16;
  }
  if (p + 8 <= p1){
    unsigned e[8], h[8];
    #pragma unroll
    for (int j = 0; j < 8; ++j) e[j] = __builtin_amdgcn_readfirstlane(edges[p + j]);
    #pragma unroll
    for (int j = 0; j < 8; ++j)
      h[j] = *(const unsigned*)(Hb + (((size_t)(e[j] & 0xFFFFu)) << 8) + L4);
    #pragma unroll
    for (int j = 0; j < 8; ++j){
      float w = bfhi(e[j]);
      acc0 = fmaf(bflo(h[j]), w, acc0);
      acc1 = fmaf(bfhi(h[j]), w, acc1);
    }
    p += 8;
  }
  if (p + 4 <= p1){
    unsigned e[4], h[4];
    #pragma unroll
    for (int j = 0; j < 4; ++j) e[j] = __builtin_amdgcn_readfirstlane(edges[p + j]);
    #pragma unroll
    for (int j = 0; j < 4; ++j)
      h[j] = *(const unsigned*)(Hb + (((size_t)(e[j] & 0xFFFFu)) << 8) + L4);
    #pragma unroll
    for (int j = 0; j < 4; ++j){
      float w = bfhi(e[j]);
      acc0 = fmaf(bflo(h[j]), w, acc0);
      acc1 = fmaf(bfhi(h[j]), w, acc1);
    }
    p += 4;
  }
  for (; p < p1; ++p){
    unsigned e = __builtin_amdgcn_readfirstlane(edges[p]);
    unsigned h2 = *(const unsigned*)(Hb + (((size_t)(e & 0xFFFFu)) << 8) + L4);
    float w = bfhi(e);
    acc0 = fmaf(bflo(h2), w, acc0);
    acc1 = fmaf(bfhi(h2), w, acc1);
  }
  if (do_relu){ acc0 = fmaxf(acc0, 0.f); acc1 = fmaxf(acc1, 0.f); }
  if (OUT_F32){
    ((float2*)((float*)out + (size_t)i * NDIM))[L] = make_float2(acc0, acc1);
  } else {
    ((unsigned*)((unsigned short*)out + (size_t)i * NDIM))[L] = (f2bf(acc1) << 16) | f2bf(acc0);
  }
}

// ---- launcher -------------------------------------------------------------
extern "C" void kernel_launch(void* const* d_in, const int* in_sizes, int n_in,
                              void* d_out, int out_size, void* d_ws, size_t ws_size,
                              hipStream_t stream){
  const float* x  = (const float*)d_in[0];
  const int*   ei = (const int*)  d_in[1];
  const float* ew = (const float*)d_in[2];
  const float* W1 = (const float*)d_in[3];
  const float* b1 = (const float*)d_in[4];
  const float* W2 = (const float*)d_in[5];
  const float* b2 = (const float*)d_in[6];
  float* out = (float*)d_out;
  int N = in_sizes[0] / NDIM;
  int E = in_sizes[2];
  int nb = (N + 1023) / 1024;                 // 49 (must be <= 64)
  int ntiles = N / 16;                        // 3125

  char* p = (char*)d_ws;
  auto alloc = [&](size_t b) -> char* { char* r = p; p += (b + 255) & ~(size_t)255; return r; };
  unsigned long long* pk = (unsigned long long*)alloc((size_t)N * 16);  // 2 tables
  float*    dis   = (float*)   alloc((size_t)N * 4);
  int*      cA    = (int*)     alloc((size_t)N * 4);
  int*      off   = (int*)     alloc((size_t)(N + 1) * 4);
  int*      bsum  = (int*)     alloc((size_t)64 * 4);
  unsigned short* rank = (unsigned short*)alloc((size_t)E * 2);
  unsigned short* Wp1 = (unsigned short*)alloc(NDIM * NDIM * 2);
  unsigned short* Wp2 = (unsigned short*)alloc(NDIM * NDIM * 2);
  unsigned* edges = (unsigned*)alloc((size_t)E * 4);
  unsigned short* R  = (unsigned short*)alloc((size_t)N * NDIM * 2);  // 12.8 MB bf16
  unsigned short* H2 = (unsigned short*)alloc((size_t)N * NDIM * 2);  // 12.8 MB bf16
  unsigned short* H1 = (unsigned short*)d_out;   // d_out low half as bf16 scratch

  k_prep0<<<(N + 255) / 256, 256, 0, stream>>>(pk, W1, W2, Wp1, Wp2, N);
  k_deg  <<<(E + 255) / 256, 256, 0, stream>>>(ei, ew, pk, rank, E, N);
  k_scan1<<<nb, 1024, 0, stream>>>(pk, off, bsum, N);
  k_scan23<<<nb, 1024, 0, stream>>>(off, cA, bsum, pk, dis, N, E, nb);
  k_place<<<NPART * 256, 256, 0, stream>>>(ei, ew, rank, dis, off, cA, edges, E, N);

  int gg = (ntiles + 3) / 4;                  // 782 blocks -> 1 tile/wave
  // layer 1: H1 = x @ W1 (bf16, d_out low half), R = relu(agg(H1) + b1)
  k_gemm_mfma<1><<<gg, 256, 0, stream>>>(x, Wp1, H1, ntiles);
  k_agg<0> <<<(N + 3) / 4, 256, 0, stream>>>(H1, off, edges, dis, b1, R, N, 1);
  // layer 2: H2 = R @ W2, out = agg(H2) + b2 (fp32)
  k_gemm_mfma<0><<<gg, 256, 0, stream>>>(R, Wp2, H2, ntiles);
  k_agg<1> <<<(N + 3) / 4, 256, 0, stream>>>(H2, off, edges, dis, b2, out, N, 0);
}

// Round 15
// 228.354 us; speedup vs baseline: 1.3931x; 1.0161x over previous
//
#include <hip/hip_runtime.h>

#define NDIM 128
#define NPART 8

typedef __attribute__((ext_vector_type(8))) short bf16x8;
typedef __attribute__((ext_vector_type(4))) float floatx4;

__device__ __forceinline__ float bflo(unsigned v){ return __uint_as_float(v << 16); }
__device__ __forceinline__ float bfhi(unsigned v){ return __uint_as_float(v & 0xffff0000u); }
__device__ __forceinline__ unsigned f2bf(float f){
  unsigned u = __float_as_uint(f);
  return (u + 0x7fffu + ((u >> 16) & 1u)) >> 16;   // RNE
}

// ---- prep0: zero pk + wprep W1,W2 (fp32 [in,out] -> bf16 B-frag image) -----
// B-frag layout: frag (kt,ct), lane L=kq*16+n15, j=0..7 -> W[kt*32+kq*8+j][ct*16+n15]
__global__ void k_prep0(unsigned long long* __restrict__ pk,
                        const float* __restrict__ W1, const float* __restrict__ W2,
                        unsigned short* __restrict__ Wp1, unsigned short* __restrict__ Wp2,
                        int n){
  int i = blockIdx.x * 256 + threadIdx.x;
  if (i < n) pk[i] = 0ULL;
  if (i < NDIM * NDIM){
    int k = i >> 7, c = i & 127;
    int kt = k >> 5, kq = (k >> 3) & 3, j = k & 7;
    int Lb = kq * 16 + (c & 15);
    int idx = (((kt * 8 + (c >> 4)) * 64) + Lb) * 8 + j;
    Wp1[idx] = (unsigned short)f2bf(W1[i]);
    Wp2[idx] = (unsigned short)f2bf(W2[i]);
  }
}

// pk[i] packs (cnt << 44) | fixed-point sum of ew (2^20 scale).
// atomic return gives this edge's within-node rank -> no atomic needed in place.
// (measured floor ~26 us: L2 atomic-throughput-bound; 2-table split neutral r14)
__global__ void k_deg(const int* __restrict__ ei, const float* __restrict__ ew,
                      unsigned long long* pk, unsigned short* __restrict__ rank, int E){
  int e = blockIdx.x * blockDim.x + threadIdx.x;
  if (e >= E) return;
  int d = ei[E + e];                         // row 1 = dst
  unsigned fx = (unsigned)__float2uint_rn(ew[e] * 1048576.0f);
  unsigned long long old = atomicAdd(&pk[d], (1ULL << 44) | (unsigned long long)fx);
  rank[e] = (unsigned short)(old >> 44);     // max degree << 65536
}

// ---- hierarchical scan -----------------------------------------------------
__global__ __launch_bounds__(1024) void k_scan1(const unsigned long long* __restrict__ pk,
                                                int* __restrict__ off,
                                                int* __restrict__ bsum, int n){
  __shared__ int wsum[16];
  int t = threadIdx.x;
  int i = blockIdx.x * 1024 + t;
  int c = (i < n) ? (int)(pk[i] >> 44) : 0;
  int lane = t & 63, w = t >> 6;
  int v = c;
  #pragma unroll
  for (int d = 1; d < 64; d <<= 1){ int u = __shfl_up(v, d); if (lane >= d) v += u; }
  if (lane == 63) wsum[w] = v;
  __syncthreads();
  if (w == 0){
    int sv = (lane < 16) ? wsum[lane] : 0;
    #pragma unroll
    for (int d = 1; d < 16; d <<= 1){ int u = __shfl_up(sv, d); if (lane >= d) sv += u; }
    if (lane < 16) wsum[lane] = sv;
  }
  __syncthreads();
  int base = (w > 0) ? wsum[w - 1] : 0;
  if (i < n) off[i] = base + v - c;
  if (t == 1023) bsum[blockIdx.x] = wsum[15];
}

// merged scan2+scan3: each block redundantly prefix-sums bsum (nb<=64) in-wave
__global__ __launch_bounds__(1024) void k_scan23(int* __restrict__ off,
                                                 const int* __restrict__ bsum,
                                                 const unsigned long long* __restrict__ pk,
                                                 float* __restrict__ dis, int n, int E, int nb){
  __shared__ int sBase;
  int t = threadIdx.x;
  if (t < 64){
    int c2 = (t < nb) ? bsum[t] : 0;
    int v2 = c2;
    #pragma unroll
    for (int d = 1; d < 64; d <<= 1){ int u = __shfl_up(v2, d); if (t >= d) v2 += u; }
    if (t == (int)blockIdx.x) sBase = v2 - c2;
  }
  __syncthreads();
  int i = blockIdx.x * 1024 + t;
  if (i == 0) off[n] = E;
  if (i >= n) return;
  off[i] += sBase;
  float deg = 1.0f + (float)(pk[i] & ((1ULL << 44) - 1)) * (1.0f / 1048576.0f);
  dis[i] = rsqrtf(deg);
}

// ---- placement: atomic-free (rank-based), dst-partitioned for XCD-local ----
// writes (full-line writebacks ~3 MB vs 56 MB unpartitioned — r6/r7 counters).
// edges[p] = (bf16(norm) << 16) | u16 src   (N < 65536)
__global__ __launch_bounds__(256) void k_place(const int* __restrict__ ei,
                                               const float* __restrict__ ew,
                                               const unsigned short* __restrict__ rank,
                                               const float* __restrict__ dis,
                                               const int* __restrict__ off,
                                               unsigned* __restrict__ edges,
                                               int E, int N){
  int pid = blockIdx.x % NPART;
  int cid = blockIdx.x / NPART;
  int C   = gridDim.x / NPART;
  int per = (E + C - 1) / C;
  int e0 = cid * per;
  int e1 = min(e0 + per, E);
  int lo = (int)(((long long)pid * N) / NPART);
  int hi = (int)(((long long)(pid + 1) * N) / NPART);
  for (int e = e0 + threadIdx.x; e < e1; e += 256){
    int d = ei[E + e];
    if (d < lo || d >= hi) continue;
    int s = ei[e];
    float w = ew[e];
    int p = off[d] + (int)rank[e];
    edges[p] = (f2bf(dis[s] * w * dis[d]) << 16) | (unsigned)s;
  }
}

// ---- MFMA GEMM: H[ntiles*16,128] = X @ W (Wp pre-swizzled bf16) ------------
template<int XF32>
__global__ __launch_bounds__(256) void k_gemm_mfma(const void* __restrict__ Xv,
                                                   const unsigned short* __restrict__ Wp,
                                                   unsigned short* __restrict__ Hout,
                                                   int ntiles){
  __shared__ unsigned short Wb[4 * 8 * 64 * 8];   // 32 KiB
  int tid = threadIdx.x;
  for (int t = tid; t < 2048; t += 256)           // plain 32 KB memcpy
    ((uint4*)Wb)[t] = ((const uint4*)Wp)[t];
  __syncthreads();

  int w = tid >> 6, L = tid & 63;
  int m = L & 15, q = L >> 4;
  for (int tile = blockIdx.x * 4 + w; tile < ntiles; tile += gridDim.x * 4){
    size_t row = (size_t)tile * 16 + m;
    floatx4 acc[8] = {};
    #pragma unroll
    for (int kt = 0; kt < 4; ++kt){
      bf16x8 a;
      if (XF32){
        const float* xp = (const float*)Xv + row * NDIM + kt * 32 + q * 8;
        float4 a0 = *(const float4*)xp;
        float4 a1 = *(const float4*)(xp + 4);
        unsigned short* as = (unsigned short*)&a;
        as[0] = f2bf(a0.x); as[1] = f2bf(a0.y); as[2] = f2bf(a0.z); as[3] = f2bf(a0.w);
        as[4] = f2bf(a1.x); as[5] = f2bf(a1.y); as[6] = f2bf(a1.z); as[7] = f2bf(a1.w);
      } else {
        a = *(const bf16x8*)((const unsigned short*)Xv + row * NDIM + kt * 32 + q * 8);
      }
      #pragma unroll
      for (int ct = 0; ct < 8; ++ct){
        bf16x8 b = *(const bf16x8*)&Wb[((kt * 8 + ct) * 64 + L) * 8];
        acc[ct] = __builtin_amdgcn_mfma_f32_16x16x32_bf16(a, b, acc[ct], 0, 0, 0);
      }
    }
    #pragma unroll
    for (int ct = 0; ct < 8; ++ct){
      #pragma unroll
      for (int r = 0; r < 4; ++r){
        size_t orow = (size_t)tile * 16 + q * 4 + r;
        Hout[orow * NDIM + ct * 16 + m] = (unsigned short)f2bf(acc[ct][r]);
      }
    }
  }
}

// ---- aggregation: 16/8/4-deep gather batching, scalar (uniform) edge loads -
// out[i] = b + H[i]*dis[i]^2 + sum_in H[src]*norm ; FMA order = p ascending
template<int OUT_F32>
__global__ __launch_bounds__(256) void k_agg(const unsigned short* __restrict__ H,
                                             const int* __restrict__ off,
                                             const unsigned* __restrict__ edges,
                                             const float* __restrict__ dis,
                                             const float* __restrict__ bias,
                                             void* __restrict__ out,
                                             int n, int do_relu){
  int g = threadIdx.x >> 6, L = threadIdx.x & 63;   // 4 nodes/block, 64 lanes/node
  int i = blockIdx.x * 4 + g;
  if (i >= n) return;
  float di = dis[i];
  float dii = di * di;
  float2 bv = ((const float2*)bias)[L];
  unsigned hv = ((const unsigned*)(H + (size_t)i * NDIM))[L];
  float acc0 = fmaf(bflo(hv), dii, bv.x);
  float acc1 = fmaf(bfhi(hv), dii, bv.y);
  int p  = __builtin_amdgcn_readfirstlane(off[i]);
  int p1 = __builtin_amdgcn_readfirstlane(off[i + 1]);
  const char* Hb = (const char*)H;
  unsigned L4 = (unsigned)L * 4u;

  while (p + 16 <= p1){
    unsigned e[16], h[16];
    #pragma unroll
    for (int j = 0; j < 16; ++j) e[j] = __builtin_amdgcn_readfirstlane(edges[p + j]);
    #pragma unroll
    for (int j = 0; j < 16; ++j)                               // 16 gathers in flight
      h[j] = *(const unsigned*)(Hb + (((size_t)(e[j] & 0xFFFFu)) << 8) + L4);
    #pragma unroll
    for (int j = 0; j < 16; ++j){
      float w = bfhi(e[j]);
      acc0 = fmaf(bflo(h[j]), w, acc0);
      acc1 = fmaf(bfhi(h[j]), w, acc1);
    }
    p += 16;
  }
  if (p + 8 <= p1){
    unsigned e[8], h[8];
    #pragma unroll
    for (int j = 0; j < 8; ++j) e[j] = __builtin_amdgcn_readfirstlane(edges[p + j]);
    #pragma unroll
    for (int j = 0; j < 8; ++j)
      h[j] = *(const unsigned*)(Hb + (((size_t)(e[j] & 0xFFFFu)) << 8) + L4);
    #pragma unroll
    for (int j = 0; j < 8; ++j){
      float w = bfhi(e[j]);
      acc0 = fmaf(bflo(h[j]), w, acc0);
      acc1 = fmaf(bfhi(h[j]), w, acc1);
    }
    p += 8;
  }
  if (p + 4 <= p1){
    unsigned e[4], h[4];
    #pragma unroll
    for (int j = 0; j < 4; ++j) e[j] = __builtin_amdgcn_readfirstlane(edges[p + j]);
    #pragma unroll
    for (int j = 0; j < 4; ++j)
      h[j] = *(const unsigned*)(Hb + (((size_t)(e[j] & 0xFFFFu)) << 8) + L4);
    #pragma unroll
    for (int j = 0; j < 4; ++j){
      float w = bfhi(e[j]);
      acc0 = fmaf(bflo(h[j]), w, acc0);
      acc1 = fmaf(bfhi(h[j]), w, acc1);
    }
    p += 4;
  }
  for (; p < p1; ++p){
    unsigned e = __builtin_amdgcn_readfirstlane(edges[p]);
    unsigned h2 = *(const unsigned*)(Hb + (((size_t)(e & 0xFFFFu)) << 8) + L4);
    float w = bfhi(e);
    acc0 = fmaf(bflo(h2), w, acc0);
    acc1 = fmaf(bfhi(h2), w, acc1);
  }
  if (do_relu){ acc0 = fmaxf(acc0, 0.f); acc1 = fmaxf(acc1, 0.f); }
  if (OUT_F32){
    ((float2*)((float*)out + (size_t)i * NDIM))[L] = make_float2(acc0, acc1);
  } else {
    ((unsigned*)((unsigned short*)out + (size_t)i * NDIM))[L] = (f2bf(acc1) << 16) | f2bf(acc0);
  }
}

// ---- launcher -------------------------------------------------------------
extern "C" void kernel_launch(void* const* d_in, const int* in_sizes, int n_in,
                              void* d_out, int out_size, void* d_ws, size_t ws_size,
                              hipStream_t stream){
  const float* x  = (const float*)d_in[0];
  const int*   ei = (const int*)  d_in[1];
  const float* ew = (const float*)d_in[2];
  const float* W1 = (const float*)d_in[3];
  const float* b1 = (const float*)d_in[4];
  const float* W2 = (const float*)d_in[5];
  const float* b2 = (const float*)d_in[6];
  float* out = (float*)d_out;
  int N = in_sizes[0] / NDIM;
  int E = in_sizes[2];
  int nb = (N + 1023) / 1024;                 // 49 (must be <= 64)
  int ntiles = N / 16;                        // 3125

  char* p = (char*)d_ws;
  auto alloc = [&](size_t b) -> char* { char* r = p; p += (b + 255) & ~(size_t)255; return r; };
  unsigned long long* pk = (unsigned long long*)alloc((size_t)N * 8);
  float*    dis   = (float*)   alloc((size_t)N * 4);
  int*      off   = (int*)     alloc((size_t)(N + 1) * 4);
  int*      bsum  = (int*)     alloc((size_t)64 * 4);
  unsigned short* rank = (unsigned short*)alloc((size_t)E * 2);
  unsigned short* Wp1 = (unsigned short*)alloc(NDIM * NDIM * 2);
  unsigned short* Wp2 = (unsigned short*)alloc(NDIM * NDIM * 2);
  unsigned* edges = (unsigned*)alloc((size_t)E * 4);
  unsigned short* R  = (unsigned short*)alloc((size_t)N * NDIM * 2);  // 12.8 MB bf16
  unsigned short* H2 = (unsigned short*)alloc((size_t)N * NDIM * 2);  // 12.8 MB bf16
  unsigned short* H1 = (unsigned short*)d_out;   // d_out low half as bf16 scratch

  k_prep0<<<(N + 255) / 256, 256, 0, stream>>>(pk, W1, W2, Wp1, Wp2, N);
  k_deg  <<<(E + 255) / 256, 256, 0, stream>>>(ei, ew, pk, rank, E);
  k_scan1<<<nb, 1024, 0, stream>>>(pk, off, bsum, N);
  k_scan23<<<nb, 1024, 0, stream>>>(off, bsum, pk, dis, N, E, nb);
  k_place<<<NPART * 256, 256, 0, stream>>>(ei, ew, rank, dis, off, edges, E, N);

  int gg = (ntiles + 3) / 4;                  // 782 blocks -> 1 tile/wave
  // layer 1: H1 = x @ W1 (bf16, d_out low half), R = relu(agg(H1) + b1)
  k_gemm_mfma<1><<<gg, 256, 0, stream>>>(x, Wp1, H1, ntiles);
  k_agg<0> <<<(N + 3) / 4, 256, 0, stream>>>(H1, off, edges, dis, b1, R, N, 1);
  // layer 2: H2 = R @ W2, out = agg(H2) + b2 (fp32)
  k_gemm_mfma<0><<<gg, 256, 0, stream>>>(R, Wp2, H2, ntiles);
  k_agg<1> <<<(N + 3) / 4, 256, 0, stream>>>(H2, off, edges, dis, b2, out, N, 0);
}